// Round 9
// baseline (189.819 us; speedup 1.0000x reference)
//
#include <hip/hip_runtime.h>

#define IMG 224
#define HW (IMG * IMG)
#define TILE 32
#define PAD 4
#define REG (TILE + 2 * PAD)   // 40: staged rows/cols per tile
#define RSA 41                 // A-table row stride in float2 units (odd)
#define TABA (REG * RSA)       // 1640 float2 per image (ch0,ch1 packed)
#define RSB 44                 // B-table row stride in floats (mult of 4)
#define TABB (REG * RSB)       // 1760 floats per image (ch2)

#define NXCD 8
#define NWG  (49 * 64)         // 3136 blocks, % 8 == 0 -> bijective swizzle

// native clang vector for __builtin_nontemporal_* (HIP_vector_type rejected)
typedef float vfloat4 __attribute__((ext_vector_type(4)));

struct Gath { float2 a0, a1, a2, a3; float b0, b1, b2, b3; };

// Issue the 8 LDS reads for one px-img tap set. Offsets are pre-clamped safe
// even when the wave will take the global fallback (oa=ob=0, dx,dy in {0,1}).
__device__ __forceinline__ Gath issue_reads(
    const float2* __restrict__ TA, const float* __restrict__ TB,
    int oa, int ob, int dx, int dy)
{
    Gath g;
    const int dA = dy * RSA, dB = dy * RSB;
    g.a0 = TA[oa];           g.a1 = TA[oa + dx];
    g.a2 = TA[oa + dA];      g.a3 = TA[oa + dx + dA];
    g.b0 = TB[ob];           g.b1 = TB[ob + dx];
    g.b2 = TB[ob + dB];      g.b3 = TB[ob + dx + dB];
    return g;
}

__global__ __launch_bounds__(256, 4) void vm_kernel(
    const float* __restrict__ im1, const float* __restrict__ im2,
    const float* __restrict__ C, const float* __restrict__ M1,
    const float* __restrict__ M2, float* __restrict__ out)
{
    __shared__ float2 tabA[2 * TABA];
    __shared__ float  tabB[2 * TABB];

    // XCD-aware swizzle (verified in R7: FETCH 150 -> 63 MB)
    const int bid     = blockIdx.x;
    const int logical = (bid & (NXCD - 1)) * (NWG / NXCD) + (bid >> 3);
    const int n       = logical / 49;
    const int tile    = logical - n * 49;

    const int x0   = (tile / 7) * TILE;
    const int y0   = (tile % 7) * TILE;
    const int t    = threadIdx.x;
    const int xlo  = x0 - PAD;
    const int ylo  = y0 - PAD;
    const int gbase = xlo + IMG * ylo;

    const float* i1n = im1 + (size_t)n * 3 * HW;
    const float* i2n = im2 + (size_t)n * 3 * HW;
    const float* Cn  = C  + (size_t)n * 2 * HW;
    const float* M1n = M1 + (size_t)n * HW;
    const float* M2n = M2 + (size_t)n * HW;

    // ---- C/M first: they feed the pre-barrier address math.
    const int tx  = t >> 3;                // 0..31 (slow coord, p / 224)
    const int ty0 = (t & 7) * 4;           // 0,4,..,28 (fast coord base)
    const int p   = (x0 + tx) * IMG + (y0 + ty0);

    const vfloat4 c0v = __builtin_nontemporal_load((const vfloat4*)(Cn + p));
    const vfloat4 c1v = __builtin_nontemporal_load((const vfloat4*)(Cn + HW + p));
    const vfloat4 m1v = __builtin_nontemporal_load((const vfloat4*)(M1n + p));
    const vfloat4 m2v = __builtin_nontemporal_load((const vfloat4*)(M2n + p));

    // ---- staging (identical to R7, verified)
#pragma unroll
    for (int img = 0; img < 2; ++img) {
        const float* src = img ? i2n : i1n;
        float2* TA = tabA + img * TABA;
        float*  TB = tabB + img * TABB;
#pragma unroll
        for (int k = 0; k < 2; ++k) {
            int e = t + 256 * k;
            if (e < 400) {                  // k=1 partial (t<144)
                int r = e / 10, s = e - r * 10;
                int gi = gbase + IMG * r + 4 * s;
                float4 a, b, c;
                if (gi >= 0 && gi <= HW - 4) {
                    a = *(const float4*)(src + gi);
                    b = *(const float4*)(src + HW + gi);
                    c = *(const float4*)(src + 2 * HW + gi);
                } else {                    // flat-clamp edge rows (rare)
#pragma unroll
                    for (int i = 0; i < 4; ++i) {
                        int g = min(max(gi + i, 0), HW - 1);
                        ((float*)&a)[i] = src[g];
                        ((float*)&b)[i] = src[HW + g];
                        ((float*)&c)[i] = src[2 * HW + g];
                    }
                }
                float2* dA = TA + r * RSA + 4 * s;
                dA[0] = make_float2(a.x, b.x);
                dA[1] = make_float2(a.y, b.y);
                dA[2] = make_float2(a.z, b.z);
                dA[3] = make_float2(a.w, b.w);
                *(float4*)(TB + r * RSB + 4 * s) = c;
            }
        }
    }

    // ---- pre-barrier: ALL 8 px-img tap addresses + fast flags. Overlaps the
    //      staging drain; post-barrier chain is then reads + FMAs only.
    const float xf = (float)(x0 + tx);
    int oAk[8], oBk[8], dxk[8], dyk[8], fak[8];
#pragma unroll
    for (int i = 0; i < 4; ++i) {
        const float yf = (float)(y0 + ty0 + i);
#pragma unroll
        for (int s2 = 0; s2 < 2; ++s2) {
            const int k = i * 2 + s2;
            const float sg = s2 ? -1.0f : 1.0f;
            float px = xf + sg * c0v[i], py = yf + sg * c1v[i];
            float fxf = floorf(px), cxf = ceilf(px);
            float fyf = floorf(py), cyf = ceilf(py);
            int gx0 = (int)fxf, gy0 = (int)fyf;
            int dx = (int)cxf - gx0, dy = (int)cyf - gy0;
            int q0 = gx0 - xlo, r0 = gy0 - ylo;
            int in = (q0 >= 0) & (q0 + dx <= REG - 1) &
                     (r0 >= 0) & (r0 + dy <= REG - 1);
            int fa = __all(in);
            fak[k] = fa;
            oAk[k] = fa ? (r0 * RSA + q0) : 0;   // safe when fallback taken
            oBk[k] = fa ? (r0 * RSB + q0) : 0;
            dxk[k] = dx;
            dyk[k] = dy;
        }
    }

    __syncthreads();                       // the ONLY barrier

    // ---- post-barrier: software-pipelined reads (1 pixel ahead, ~24-48
    //      ds_reads in flight). Weights recomputed at consume (cheap VALU).
    float acc0[4], acc1[4], acc2[4];

    Gath gA = issue_reads(tabA,        tabB,        oAk[0], oBk[0], dxk[0], dyk[0]);
    Gath gB = issue_reads(tabA + TABA, tabB + TABB, oAk[1], oBk[1], dxk[1], dyk[1]);

#pragma unroll
    for (int i = 0; i < 4; ++i) {
        Gath nA, nB;
        if (i < 3) {
            nA = issue_reads(tabA,        tabB,
                             oAk[2 * i + 2], oBk[2 * i + 2],
                             dxk[2 * i + 2], dyk[2 * i + 2]);
            nB = issue_reads(tabA + TABA, tabB + TABB,
                             oAk[2 * i + 3], oBk[2 * i + 3],
                             dxk[2 * i + 3], dyk[2 * i + 3]);
        }

        const float yf = (float)(y0 + ty0 + i);
        float r0c = 0.0f, r1c = 0.0f, r2c = 0.0f;

#pragma unroll
        for (int s2 = 0; s2 < 2; ++s2) {
            const int k = i * 2 + s2;
            const float mi = s2 ? m2v[i] : m1v[i];
            const float sg = s2 ? -1.0f : 1.0f;
            // recompute weights (from registers; overlaps lgkmcnt wait)
            float px = xf + sg * c0v[i], py = yf + sg * c1v[i];
            float fxf = floorf(px), cxf = ceilf(px);
            float fyf = floorf(py), cyf = ceilf(py);
            float wfx = 1.0f - (px - fxf), wcx = 1.0f - (cxf - px);
            float wfy = 1.0f - (py - fyf), wcy = 1.0f - (cyf - py);
            float w0 = wfx * wfy, w1 = wcx * wfy;
            float w2 = wfx * wcy, w3 = wcx * wcy;

            const Gath& g = s2 ? gB : gA;
            if (fak[k]) {
                r0c += mi * (w0 * g.a0.x + w1 * g.a1.x + w2 * g.a2.x + w3 * g.a3.x);
                r1c += mi * (w0 * g.a0.y + w1 * g.a1.y + w2 * g.a2.y + w3 * g.a3.y);
                r2c += mi * (w0 * g.b0   + w1 * g.b1   + w2 * g.b2   + w3 * g.b3);
            } else {   // rare: displacement beyond PAD -> global clamped gather
                const float* src = s2 ? i2n : i1n;
                int gx0 = (int)fxf, gy0 = (int)fyf;
                int dx = (int)cxf - gx0, dy = (int)cyf - gy0;
                int i0 = min(max(gx0      + IMG * gy0,        0), HW - 1);
                int i1 = min(max(gx0 + dx + IMG * gy0,        0), HW - 1);
                int i2 = min(max(gx0      + IMG * (gy0 + dy), 0), HW - 1);
                int i3 = min(max(gx0 + dx + IMG * (gy0 + dy), 0), HW - 1);
                r0c += mi * (w0 * src[i0] + w1 * src[i1] +
                             w2 * src[i2] + w3 * src[i3]);
                r1c += mi * (w0 * src[HW + i0] + w1 * src[HW + i1] +
                             w2 * src[HW + i2] + w3 * src[HW + i3]);
                r2c += mi * (w0 * src[2 * HW + i0] + w1 * src[2 * HW + i1] +
                             w2 * src[2 * HW + i2] + w3 * src[2 * HW + i3]);
            }
        }
        acc0[i] = r0c; acc1[i] = r1c; acc2[i] = r2c;

        gA = nA; gB = nB;
    }

    // coalesced non-temporal float4 stores
    float* on = out + (size_t)n * 3 * HW;
    vfloat4 s0 = {acc0[0], acc0[1], acc0[2], acc0[3]};
    vfloat4 s1 = {acc1[0], acc1[1], acc1[2], acc1[3]};
    vfloat4 s2 = {acc2[0], acc2[1], acc2[2], acc2[3]};
    __builtin_nontemporal_store(s0, (vfloat4*)(on + p));
    __builtin_nontemporal_store(s1, (vfloat4*)(on + HW + p));
    __builtin_nontemporal_store(s2, (vfloat4*)(on + 2 * HW + p));
}

extern "C" void kernel_launch(void* const* d_in, const int* in_sizes, int n_in,
                              void* d_out, int out_size, void* d_ws, size_t ws_size,
                              hipStream_t stream) {
    const float* im1 = (const float*)d_in[0];
    const float* im2 = (const float*)d_in[1];
    const float* C   = (const float*)d_in[2];
    const float* M1  = (const float*)d_in[3];
    const float* M2  = (const float*)d_in[4];
    float* out = (float*)d_out;
    vm_kernel<<<dim3(NWG), 256, 0, stream>>>(im1, im2, C, M1, M2, out);
}

// Round 10
// 170.292 us; speedup vs baseline: 1.1147x; 1.1147x over previous
//
#include <hip/hip_runtime.h>

#define IMG 224
#define HW (IMG * IMG)
#define TILE 32
#define PAD 4
#define REG (TILE + 2 * PAD)       // 40: staged rows/cols per tile
#define RSTP (REG + 1)             // 41: LDS row stride in float4 units
                                   //     (41 mod 8 = 1 -> row steps walk all
                                   //      8 bank-quads: b128 reads near floor)
#define TAB (REG * RSTP)           // 1640 float4 per packed image table

#define NXCD 8
#define NWG  (49 * 64)             // 3136 blocks, % 8 == 0 -> bijective swizzle

// native clang vector for __builtin_nontemporal_* (HIP_vector_type rejected)
typedef float vfloat4 __attribute__((ext_vector_type(4)));

__global__ __launch_bounds__(256, 3) void vm_kernel(
    const float* __restrict__ im1, const float* __restrict__ im2,
    const float* __restrict__ C, const float* __restrict__ M1,
    const float* __restrict__ M2, float* __restrict__ out)
{
    // Channel-packed tiles: pixel -> {ch0, ch1, ch2, 0} (16 B). One table per
    // image; ONE ds_read_b128 per bilinear tap gives all 3 channels.
    // 2 * 1640 * 16 = 52,480 B -> 3 blocks/CU.
    __shared__ float4 tab[2 * TAB];

    // XCD-aware swizzle (verified R7: FETCH 150 -> 63 MB): each XCD owns a
    // contiguous logical range = 8 whole batch images (49 tiles each).
    const int bid     = blockIdx.x;
    const int logical = (bid & (NXCD - 1)) * (NWG / NXCD) + (bid >> 3);
    const int n       = logical / 49;
    const int tile    = logical - n * 49;  // 0..48

    const int x0   = (tile / 7) * TILE;    // gather col coord (p / 224)
    const int y0   = (tile % 7) * TILE;    // gather row coord (p % 224)
    const int t    = threadIdx.x;
    const int xlo  = x0 - PAD;
    const int ylo  = y0 - PAD;
    const int gbase = xlo + IMG * ylo;     // flat index of tile origin

    const float* i1n = im1 + (size_t)n * 3 * HW;
    const float* i2n = im2 + (size_t)n * 3 * HW;
    const float* Cn  = C  + (size_t)n * 2 * HW;
    const float* M1n = M1 + (size_t)n * HW;
    const float* M2n = M2 + (size_t)n * HW;

    // ---- phase 1: stage both packed tables. Each unit = 4 consecutive pixels
    //      of one row: 3 float4 global loads (one per channel), 4 ds_write_b128.
    //      400 units per image; lanes consecutive in s -> coalesced 160B runs.
#pragma unroll
    for (int img = 0; img < 2; ++img) {
        const float* src = img ? i2n : i1n;
        float4* T = tab + img * TAB;
#pragma unroll
        for (int k = 0; k < 2; ++k) {
            int e = t + 256 * k;
            if (e < 400) {                  // k=1 partial (t<144)
                int r = e / 10, s = e - r * 10;
                int gi = gbase + IMG * r + 4 * s;
                float4 a, b, c;
                if (gi >= 0 && gi <= HW - 4) {
                    a = *(const float4*)(src + gi);
                    b = *(const float4*)(src + HW + gi);
                    c = *(const float4*)(src + 2 * HW + gi);
                } else {                    // flat-clamp edge rows (rare tiles)
#pragma unroll
                    for (int i = 0; i < 4; ++i) {
                        int g = min(max(gi + i, 0), HW - 1);
                        ((float*)&a)[i] = src[g];
                        ((float*)&b)[i] = src[HW + g];
                        ((float*)&c)[i] = src[2 * HW + g];
                    }
                }
                float4* dst = T + r * RSTP + 4 * s;
                dst[0] = make_float4(a.x, b.x, c.x, 0.0f);
                dst[1] = make_float4(a.y, b.y, c.y, 0.0f);
                dst[2] = make_float4(a.z, b.z, c.z, 0.0f);
                dst[3] = make_float4(a.w, b.w, c.w, 0.0f);
            }
        }
    }

    // ---- C/M straight to registers as vfloat4 non-temporal (read-once data,
    //      keep L2 for the image halo). Thread owns 4 consecutive ty.
    const int tx  = t >> 3;                // 0..31 (slow coord, p / 224)
    const int ty0 = (t & 7) * 4;           // 0,4,..,28 (fast coord base)
    const int p   = (x0 + tx) * IMG + (y0 + ty0);

    const vfloat4 c0v = __builtin_nontemporal_load((const vfloat4*)(Cn + p));
    const vfloat4 c1v = __builtin_nontemporal_load((const vfloat4*)(Cn + HW + p));
    const vfloat4 m1v = __builtin_nontemporal_load((const vfloat4*)(M1n + p));
    const vfloat4 m2v = __builtin_nontemporal_load((const vfloat4*)(M2n + p));

    __syncthreads();                       // the ONLY barrier

    // ---- phase 2: 4 pixels per thread, one ds_read_b128 per tap gives all
    //      3 channels (32 LDS reads total vs 64 in the pair layout).
    const float xf = (float)(x0 + tx);
    float acc0[4], acc1[4], acc2[4];

#pragma unroll
    for (int i = 0; i < 4; ++i) {
        const float yf  = (float)(y0 + ty0 + i);
        const float cc0 = c0v[i];
        const float cc1 = c1v[i];
        const float m1i = m1v[i];
        const float m2i = m2v[i];
        float r0c, r1c, r2c;

        {   // +C on im1
            float px = xf + cc0, py = yf + cc1;
            float fx = floorf(px), cx = ceilf(px);
            float fy = floorf(py), cy = ceilf(py);
            float wfx = 1.0f - (px - fx), wcx = 1.0f - (cx - px);
            float wfy = 1.0f - (py - fy), wcy = 1.0f - (cy - py);
            float w0 = wfx * wfy, w1 = wcx * wfy;
            float w2 = wfx * wcy, w3 = wcx * wcy;
            int gx0 = (int)fx, gy0 = (int)fy;
            int dx = (int)cx - gx0, dy = (int)cy - gy0;
            int q0 = gx0 - xlo, r0 = gy0 - ylo;
            int in = (q0 >= 0) & (q0 + dx <= REG - 1) &
                     (r0 >= 0) & (r0 + dy <= REG - 1);
            if (__all(in)) {
                int o = r0 * RSTP + q0;
                float4 t0 = tab[o],             t1 = tab[o + dx];
                float4 t2 = tab[o + dy * RSTP], t3 = tab[o + dx + dy * RSTP];
                r0c = m1i * (w0 * t0.x + w1 * t1.x + w2 * t2.x + w3 * t3.x);
                r1c = m1i * (w0 * t0.y + w1 * t1.y + w2 * t2.y + w3 * t3.y);
                r2c = m1i * (w0 * t0.z + w1 * t1.z + w2 * t2.z + w3 * t3.z);
            } else {   // rare: displacement beyond PAD -> global clamped gather
                int i0 = min(max(gx0      + IMG * gy0,        0), HW - 1);
                int i1 = min(max(gx0 + dx + IMG * gy0,        0), HW - 1);
                int i2 = min(max(gx0      + IMG * (gy0 + dy), 0), HW - 1);
                int i3 = min(max(gx0 + dx + IMG * (gy0 + dy), 0), HW - 1);
                r0c = m1i * (w0 * i1n[i0] + w1 * i1n[i1] +
                             w2 * i1n[i2] + w3 * i1n[i3]);
                r1c = m1i * (w0 * i1n[HW + i0] + w1 * i1n[HW + i1] +
                             w2 * i1n[HW + i2] + w3 * i1n[HW + i3]);
                r2c = m1i * (w0 * i1n[2 * HW + i0] + w1 * i1n[2 * HW + i1] +
                             w2 * i1n[2 * HW + i2] + w3 * i1n[2 * HW + i3]);
            }
        }
        {   // -C on im2
            float px = xf - cc0, py = yf - cc1;
            float fx = floorf(px), cx = ceilf(px);
            float fy = floorf(py), cy = ceilf(py);
            float wfx = 1.0f - (px - fx), wcx = 1.0f - (cx - px);
            float wfy = 1.0f - (py - fy), wcy = 1.0f - (cy - py);
            float w0 = wfx * wfy, w1 = wcx * wfy;
            float w2 = wfx * wcy, w3 = wcx * wcy;
            int gx0 = (int)fx, gy0 = (int)fy;
            int dx = (int)cx - gx0, dy = (int)cy - gy0;
            int q0 = gx0 - xlo, r0 = gy0 - ylo;
            int in = (q0 >= 0) & (q0 + dx <= REG - 1) &
                     (r0 >= 0) & (r0 + dy <= REG - 1);
            if (__all(in)) {
                const float4* TB = tab + TAB;
                int o = r0 * RSTP + q0;
                float4 t0 = TB[o],             t1 = TB[o + dx];
                float4 t2 = TB[o + dy * RSTP], t3 = TB[o + dx + dy * RSTP];
                r0c += m2i * (w0 * t0.x + w1 * t1.x + w2 * t2.x + w3 * t3.x);
                r1c += m2i * (w0 * t0.y + w1 * t1.y + w2 * t2.y + w3 * t3.y);
                r2c += m2i * (w0 * t0.z + w1 * t1.z + w2 * t2.z + w3 * t3.z);
            } else {
                int i0 = min(max(gx0      + IMG * gy0,        0), HW - 1);
                int i1 = min(max(gx0 + dx + IMG * gy0,        0), HW - 1);
                int i2 = min(max(gx0      + IMG * (gy0 + dy), 0), HW - 1);
                int i3 = min(max(gx0 + dx + IMG * (gy0 + dy), 0), HW - 1);
                r0c += m2i * (w0 * i2n[i0] + w1 * i2n[i1] +
                              w2 * i2n[i2] + w3 * i2n[i3]);
                r1c += m2i * (w0 * i2n[HW + i0] + w1 * i2n[HW + i1] +
                              w2 * i2n[HW + i2] + w3 * i2n[HW + i3]);
                r2c += m2i * (w0 * i2n[2 * HW + i0] + w1 * i2n[2 * HW + i1] +
                              w2 * i2n[2 * HW + i2] + w3 * i2n[2 * HW + i3]);
            }
        }
        acc0[i] = r0c; acc1[i] = r1c; acc2[i] = r2c;
    }

    // coalesced non-temporal float4 stores (lanes consecutive in ty0)
    float* on = out + (size_t)n * 3 * HW;
    vfloat4 s0 = {acc0[0], acc0[1], acc0[2], acc0[3]};
    vfloat4 s1 = {acc1[0], acc1[1], acc1[2], acc1[3]};
    vfloat4 s2 = {acc2[0], acc2[1], acc2[2], acc2[3]};
    __builtin_nontemporal_store(s0, (vfloat4*)(on + p));
    __builtin_nontemporal_store(s1, (vfloat4*)(on + HW + p));
    __builtin_nontemporal_store(s2, (vfloat4*)(on + 2 * HW + p));
}

extern "C" void kernel_launch(void* const* d_in, const int* in_sizes, int n_in,
                              void* d_out, int out_size, void* d_ws, size_t ws_size,
                              hipStream_t stream) {
    const float* im1 = (const float*)d_in[0];
    const float* im2 = (const float*)d_in[1];
    const float* C   = (const float*)d_in[2];
    const float* M1  = (const float*)d_in[3];
    const float* M2  = (const float*)d_in[4];
    float* out = (float*)d_out;
    vm_kernel<<<dim3(NWG), 256, 0, stream>>>(im1, im2, C, M1, M2, out);
}